// Round 9
// baseline (407.985 us; speedup 1.0000x reference)
//
#include <hip/hip_runtime.h>
#include <hip/hip_fp16.h>
#include <cstdint>
#include <cstddef>

typedef unsigned long long u64;
typedef unsigned int u32;
typedef __attribute__((ext_vector_type(8))) _Float16 f16x8;
typedef __attribute__((ext_vector_type(4))) float f32x4;

#define NANCHORS 39375
#define PRE_NMS  2000
#define POST_NMS 300
#define CAND_CAP 4096
#define MPAD 2048          // padded row count of mask matrix
#define UNEG 0x007FFFFFu   // f2u(-inf)
#define NPIX 26250         // 2 batches x 13125 pixels

__device__ __forceinline__ u32 f2u(float f) {
  u32 u = __float_as_uint(f);
  return (u & 0x80000000u) ? ~u : (u | 0x80000000u);
}

// async global->LDS, 16B per lane. LDS dest must be WAVE-UNIFORM base; HW adds lane*16.
#define GLOAD16(gp, lp) __builtin_amdgcn_global_load_lds( \
    (const __attribute__((address_space(1))) u32*)(const void*)(gp), \
    (__attribute__((address_space(3))) u32*)(void*)(lp), 16, 0, 0)

// 16-lane rotate-reduce on the VALU pipe (DPP row_ror) — does NOT touch the LDS pipe.
#define DPP_SUM16(v) do { \
  v += __int_as_float(__builtin_amdgcn_update_dpp(0, __float_as_int(v), 0x128, 0xf, 0xf, true)); \
  v += __int_as_float(__builtin_amdgcn_update_dpp(0, __float_as_int(v), 0x124, 0xf, 0xf, true)); \
  v += __int_as_float(__builtin_amdgcn_update_dpp(0, __float_as_int(v), 0x122, 0xf, 0xf, true)); \
  v += __int_as_float(__builtin_amdgcn_update_dpp(0, __float_as_int(v), 0x121, 0xf, 0xf, true)); \
} while (0)

// ---------------- prep: xsplit | wsplit | ringzero | anchor-copy | ticket-zero ----------
// All five sub-tasks are mutually independent; fused into one grid (branch on blockIdx,
// uniform per block so the xsplit barrier is legal). Replaces 4 launches + memset.
__global__ __launch_bounds__(256) void prep_kernel(
    const float* __restrict__ f0, const float* __restrict__ f1, const float* __restrict__ f2,
    const float* __restrict__ w, const float* __restrict__ anchors,
    short* __restrict__ xh, short* __restrict__ xl,
    short* __restrict__ wh, short* __restrict__ wl,
    float* __restrict__ out_anchors, int* __restrict__ ticket)
{
  int blk = blockIdx.x;
  int tid = threadIdx.x;
  if (blk < 1656) {
    // ---- xsplit: NCHW f32 -> padded channels-last fp16 hi/lo ----
    __shared__ float tile[64][65];
    int t = blk;
    int HW, W, W2, np; const float* fp; int AB, ABS;
    if (t < 1256)      { HW = 10000; W = 100; W2 = 102; np = 157; fp = f0; AB = 0;       ABS = 2663424; }
    else if (t < 1576) { t -= 1256; HW = 2500; W = 50; W2 = 52; np = 40; fp = f1; AB = 5326848; ABS = 692224; }
    else               { t -= 1576; HW = 625;  W = 25; W2 = 27; np = 10; fp = f2; AB = 6711296; ABS = 186624; }
    int posb = t % np, r = t / np;
    int ci0 = (r & 3) * 64, b = r >> 2;
    int pos0 = posb * 64;
    int lane = tid & 63, wv = tid >> 6;
    int rp = pos0 + lane; if (rp >= HW) rp = HW - 1;
    const float* src = fp + (size_t)(b * 256 + ci0) * HW;
#pragma unroll
    for (int p = 0; p < 16; ++p) {
      int cl = wv * 16 + p;
      tile[cl][lane] = src[(size_t)cl * HW + rp];
    }
    __syncthreads();
    int pix = tid >> 2, cq = tid & 3;
    int pos = pos0 + pix;
    if (pos < HW) {
      int y = pos / W, x = pos - y * W;
      size_t ob = (size_t)AB + (size_t)b * ABS + ((size_t)((y + 1) * W2 + (x + 1))) * 256 + ci0 + cq * 16;
      __align__(16) short hs[16], ls[16];
#pragma unroll
      for (int j = 0; j < 16; ++j) {
        float v = tile[cq * 16 + j][pix];
        __half h = __float2half(v);
        __half l = __float2half((v - __half2float(h)) * 2048.0f);
        hs[j] = __half_as_short(h);
        ls[j] = __half_as_short(l);
      }
      *(int4*)(xh + ob) = ((int4*)hs)[0];
      *(int4*)(xh + ob + 8) = ((int4*)hs)[1];
      *(int4*)(xl + ob) = ((int4*)ls)[0];
      *(int4*)(xl + ob + 8) = ((int4*)ls)[1];
    }
  } else if (blk < 3960) {
    // ---- wsplit: [co][ci][tap] f32 -> B^T [tap][co][ci] fp16 hi/lo ----
    int idx = (blk - 1656) * 256 + tid;        // < 589824 exactly
    int tap = idx >> 16, co = (idx >> 8) & 255, ci = idx & 255;
    float v = w[(size_t)co * 2304 + ci * 9 + tap];
    __half h = __float2half(v);
    __half l = __float2half((v - __half2float(h)) * 2048.0f);
    wh[idx] = __half_as_short(h);
    wl[idx] = __half_as_short(l);
  } else if (blk < 4316) {
    // ---- ringzero: zero the spatial pad ring of xth/xtl ----
    int g = (blk - 3960) * 256 + tid;          // < 91136 = 1424*64 exactly
    int t = g >> 6, ln = g & 63;
    int b = t / 712, i = t % 712;
    int W2, AB, ABS;
    if (i < 404)      { W2 = 102; AB = 0;       ABS = 2663424; }
    else if (i < 608) { i -= 404; W2 = 52; AB = 5326848; ABS = 692224; }
    else              { i -= 608; W2 = 27; AB = 6711296; ABS = 186624; }
    int y, x;
    if (i < W2)          { y = 0;      x = i; }
    else if (i < 2 * W2) { y = W2 - 1; x = i - W2; }
    else { int j = i - 2 * W2; y = 1 + (j >> 1); x = (j & 1) ? (W2 - 1) : 0; }
    size_t base = (size_t)AB + (size_t)b * ABS + ((size_t)(y * W2 + x)) * 256 + ln * 4;
    int2 z = {0, 0};
    *(int2*)(xh + base) = z;
    *(int2*)(xl + base) = z;
  } else if (blk < 4932) {
    // ---- anchor copy ----
    int t = (blk - 4316) * 256 + tid;
    if (t < 157500) out_anchors[t] = anchors[t];
  } else {
    // ---- ticket zero (re-zeroed every iteration, before gemmconv) ----
    if (tid < 256) ticket[tid] = 0;
  }
}

// ---------------- conv 3x3 implicit-GEMM + fused head projection + last-block decode ----
// Core: R4-proven 256thr/4wave 128x128 tile, A+B LDS-staged, XOR-swizzled (LDS-pipe-bound
// at MfmaUtil ~45%; direct-global A regressed to 18% — R5). Epilogue projects 256ch->18
// on VALU (DPP reduce) into proj2[4][NPIX][20]. NEW: the 2 sibling blocks (nb=0/1) of a
// 128px tile ticket via device-scope atomic; the last one acquires and decodes the tile
// (verbatim decode math, fixed 4-slot sum order) — removes the decode launch + 8.4MB
// proj2 HBM round-trip.
__global__ __launch_bounds__(256, 2) void gemmconv_kernel(
    const short* __restrict__ xh, const short* __restrict__ xl,
    const short* __restrict__ wh, const short* __restrict__ wl,
    const float* __restrict__ bias,
    const float* __restrict__ loc_w, const float* __restrict__ score_w,
    const float* __restrict__ loc_b, const float* __restrict__ score_b,
    const float* __restrict__ anchors, const int* __restrict__ imgh, const int* __restrict__ imgw,
    float* __restrict__ proj2, int* __restrict__ ticket,
    float* __restrict__ out_locs, float* __restrict__ out_scores,
    float* __restrict__ boxes, u32* __restrict__ ukey)
{
  __shared__ __align__(16) short smem[32768];  // Ah[128][64] | Al | Bh[128][64] | Bl

  int lb = (blockIdx.x & 7) * 52 + (blockIdx.x >> 3);
  int tix = lb >> 1;                           // ticket id: shared by nb=0/1 siblings
  int HW, W, W2, AB, ABS, lvlbase, base_row;
  if (lb < 316)      { HW = 10000; W = 100; W2 = 102; AB = 0;       ABS = 2663424; lvlbase = 0;     base_row = 0; }
  else if (lb < 396) { lb -= 316; HW = 2500; W = 50; W2 = 52; AB = 5326848; ABS = 692224; lvlbase = 10000; base_row = 30000; }
  else               { lb -= 396; HW = 625;  W = 25; W2 = 27; AB = 6711296; ABS = 186624; lvlbase = 12500; base_row = 37500; }
  int mb = lb >> 2, b = (lb >> 1) & 1, nb = lb & 1;
  int pos0 = mb * 128, co0 = nb * 128;

  int tid = threadIdx.x;
  int s = tid & 7, mrow = tid >> 3;
  int aoff[4], boff[4];
#pragma unroll
  for (int i = 0; i < 4; ++i) {
    int m = i * 32 + mrow;
    int pos = pos0 + m; if (pos >= HW) pos = HW - 1;   // tail rows: clamp (store is masked)
    int y = pos / W, x = pos - y * W;
    aoff[i] = AB + b * ABS + (y * W2 + x) * 256 + ((s ^ (m & 7)) << 3);
    boff[i] = ((co0 + m) << 8) + ((s ^ (m & 7)) << 3);
  }
  int wv = tid >> 6, lane = tid & 63;
  int lr = lane & 15, lk = lane >> 4;
  int wr = wv >> 1, wc = wv & 1;
  int rA0 = wr * 64 + lr, rB0 = wc * 64 + lr;
  int cs = (lr & 7) << 4;
  int c0 = ((lk * 16) ^ cs) >> 1;
  int c1 = ((64 + lk * 16) ^ cs) >> 1;

  f32x4 acc1[4][4], acc2[4][4];
  f32x4 zro = {0.f, 0.f, 0.f, 0.f};
#pragma unroll
  for (int i = 0; i < 4; ++i)
#pragma unroll
    for (int j = 0; j < 4; ++j) { acc1[i][j] = zro; acc2[i][j] = zro; }

  for (int cc = 0; cc < 36; ++cc) {
    int tap = cc >> 2, cq = cc & 3;
    int ty = tap / 3, tx = tap - ty * 3;
    int adel = (ty * W2 + tx) * 256 + (cq << 6);
    int bdel = (tap << 16) + (cq << 6);
    if (cc) __syncthreads();
#pragma unroll
    for (int i = 0; i < 4; ++i) {
      int d = i * 2048 + wv * 512;
      GLOAD16(xh + aoff[i] + adel, smem + d);
      GLOAD16(xl + aoff[i] + adel, smem + 8192 + d);
      GLOAD16(wh + boff[i] + bdel, smem + 16384 + d);
      GLOAD16(wl + boff[i] + bdel, smem + 24576 + d);
    }
    __syncthreads();
#pragma unroll
    for (int k2 = 0; k2 < 2; ++k2) {
      int ck = k2 ? c1 : c0;
      f16x8 ah[4], al[4], bh[4], bl[4];
#pragma unroll
      for (int q = 0; q < 4; ++q) {
        int ro = (rA0 + q * 16) * 64 + ck;
        ah[q] = *(const f16x8*)(smem + ro);
        al[q] = *(const f16x8*)(smem + 8192 + ro);
        int rb = (rB0 + q * 16) * 64 + ck;
        bh[q] = *(const f16x8*)(smem + 16384 + rb);
        bl[q] = *(const f16x8*)(smem + 24576 + rb);
      }
#pragma unroll
      for (int m4 = 0; m4 < 4; ++m4)
#pragma unroll
        for (int n4 = 0; n4 < 4; ++n4) {
          acc1[m4][n4] = __builtin_amdgcn_mfma_f32_16x16x32_f16(ah[m4], bh[n4], acc1[m4][n4], 0, 0, 0);
          acc2[m4][n4] = __builtin_amdgcn_mfma_f32_16x16x32_f16(ah[m4], bl[n4], acc2[m4][n4], 0, 0, 0);
          acc2[m4][n4] = __builtin_amdgcn_mfma_f32_16x16x32_f16(al[m4], bh[n4], acc2[m4][n4], 0, 0, 0);
        }
    }
  }

  // ---- fused head projection epilogue (no h store) ----
  float br[4];
#pragma unroll
  for (int n4 = 0; n4 < 4; ++n4) br[n4] = bias[co0 + wc * 64 + n4 * 16 + lr];
  float* pslot = proj2 + (size_t)(nb * 2 + wc) * NPIX * 20;
  int Pbase = b * 13125 + lvlbase;

#pragma unroll 1
  for (int half = 0; half < 2; ++half) {
    float wpr[4][9];
#pragma unroll
    for (int n4 = 0; n4 < 4; ++n4) {
      int c = co0 + wc * 64 + n4 * 16 + lr;
#pragma unroll
      for (int oo = 0; oo < 9; ++oo) {
        int o = half * 9 + oo;
        wpr[n4][oo] = (o < 12) ? loc_w[o * 256 + c] : score_w[(o - 12) * 256 + c];
      }
    }
#pragma unroll
    for (int m4 = 0; m4 < 4; ++m4) {
#pragma unroll
      for (int j = 0; j < 4; ++j) {
        int pos = pos0 + wr * 64 + m4 * 16 + lk * 4 + j;   // C: row=(lane>>4)*4+reg
        bool ok = pos < HW;
        float po[9];
#pragma unroll
        for (int oo = 0; oo < 9; ++oo) po[oo] = 0.f;
#pragma unroll
        for (int n4 = 0; n4 < 4; ++n4) {
          float h = acc1[m4][n4][j] + acc2[m4][n4][j] * 4.8828125e-4f + br[n4];
          h = ok ? fmaxf(h, 0.f) : 0.f;
#pragma unroll
          for (int oo = 0; oo < 9; ++oo) po[oo] = fmaf(h, wpr[n4][oo], po[oo]);
        }
#pragma unroll
        for (int oo = 0; oo < 9; ++oo) DPP_SUM16(po[oo]);
        if (ok && lr < 9) {
          float out = po[0];                   // static-index select (rule #20)
#pragma unroll
          for (int oo = 1; oo < 9; ++oo) if (lr == oo) out = po[oo];
          pslot[(size_t)(Pbase + pos) * 20 + half * 9 + lr] = out;
        }
      }
    }
  }

  // ---- last-block-per-tile decode (release/acquire ticket, device scope) ----
  __shared__ int sh_do;
  __threadfence();                             // release: my proj2 stores visible
  if (tid == 0) sh_do = (atomicAdd(&ticket[tix], 1) == 1) ? 1 : 0;
  __syncthreads();
  if (sh_do) {
    __threadfence();                           // acquire: sibling's proj2 stores visible
    int px = tid;                              // 128 pixels; threads 128..255 idle
    if (px < 128) {
      int pos = pos0 + px;
      if (pos < HW) {
        int P = b * 13125 + lvlbase + pos;
        float sarr[18];
#pragma unroll
        for (int o = 0; o < 18; ++o)
          sarr[o] = proj2[(size_t)P * 20 + o]
                  + proj2[(size_t)NPIX * 20 + (size_t)P * 20 + o]
                  + proj2[(size_t)2 * NPIX * 20 + (size_t)P * 20 + o]
                  + proj2[(size_t)3 * NPIX * 20 + (size_t)P * 20 + o];
        float IH = (float)(*imgh), IW = (float)(*imgw);
#pragma unroll
        for (int a = 0; a < 3; ++a) {
          float l0 = sarr[4 * a + 0] + loc_b[4 * a + 0];
          float l1 = sarr[4 * a + 1] + loc_b[4 * a + 1];
          float l2 = sarr[4 * a + 2] + loc_b[4 * a + 2];
          float l3 = sarr[4 * a + 3] + loc_b[4 * a + 3];
          float sc0 = sarr[12 + 2 * a + 0] + score_b[2 * a + 0];
          float sc1 = sarr[12 + 2 * a + 1] + score_b[2 * a + 1];

          int row = base_row + pos * 3 + a;
          size_t g = (size_t)b * NANCHORS + row;
          *(float4*)(out_locs + g * 4) = make_float4(l0, l1, l2, l3);
          out_scores[g * 2 + 0] = sc0; out_scores[g * 2 + 1] = sc1;

          float mx = fmaxf(sc0, sc1);
          float e0 = expf(sc0 - mx), e1 = expf(sc1 - mx);
          float fg = e1 / (e0 + e1);

          const float* an = anchors + (size_t)row * 4;
          float a0 = an[0], a1 = an[1], a2 = an[2], a3 = an[3];
          float sh = a2 - a0, sw = a3 - a1;
          float cy = a0 + 0.5f * sh, cx = a1 + 0.5f * sw;
          float ncy = l0 * sh + cy, ncx = l1 * sw + cx;
          float nh = expf(l2) * sh, nw = expf(l3) * sw;
          float y1 = fminf(fmaxf(ncy - 0.5f * nh, 0.f), IH);
          float x1 = fminf(fmaxf(ncx - 0.5f * nw, 0.f), IW);
          float y2 = fminf(fmaxf(ncy + 0.5f * nh, 0.f), IH);
          float x2 = fminf(fmaxf(ncx + 0.5f * nw, 0.f), IW);
          bool valid = ((y2 - y1) >= 16.0f) && ((x2 - x1) >= 16.0f);
          float scm = valid ? fg : -__builtin_inff();

          *(float4*)(boxes + g * 4) = make_float4(y1, x1, y2, x2);
          ukey[g] = f2u(scm);
        }
      }
    }
  }
}

// ---------------- merged radix-select + bitonic sort, v2 --------------------------------
__global__ __launch_bounds__(1024) void selectsort_kernel(
    const u32* __restrict__ ukey, const float* __restrict__ boxes,
    float* __restrict__ topbox, u64* __restrict__ sup0)
{
  int b = blockIdx.x, tid = threadIdx.x;
  int lane = tid & 63;
  const u32* u = ukey + (size_t)b * NANCHORS;
  __shared__ u32 hist[256];
  __shared__ u32 sh_prefix;
  __shared__ int sh_rem;
  __shared__ int sh_cnt;
  __shared__ u64 key[CAND_CAP];
  __shared__ unsigned char validf[2048];

  u32 val[39];                         // 39375 = 38*1024 + 463
#pragma unroll
  for (int k = 0; k < 38; ++k) val[k] = u[tid + k * 1024];
  val[38] = (tid < 463) ? u[tid + 38912] : 0u;

  u32 prefix = 0; int rem = PRE_NMS;
#pragma unroll 1
  for (int pass = 0; pass < 4; ++pass) {
    int shift = 24 - 8 * pass;
    if (tid < 256) hist[tid] = 0;
    __syncthreads();
    u32 himask = (pass == 0) ? 0u : (0xFFFFFFFFu << (shift + 8));
    u32 pmask = prefix & himask;
#pragma unroll
    for (int k = 0; k < 39; ++k) {
      bool live = (k < 38) || (tid < 463);
      u32 v = val[k];
      bool m = live && ((v & himask) == pmask);
      u32 bin = (v >> shift) & 255u;
      u64 actm = __ballot(m);
      if (actm) {
        int src = __ffsll(actm) - 1;
        u32 binf = __shfl(bin, src, 64);
        bool same = m && (bin == binf);
        u64 sm = __ballot(same);
        if (same) {
          if (lane == __ffsll(sm) - 1)
            atomicAdd(&hist[binf], (u32)__popcll(sm));
        } else if (m) {
          atomicAdd(&hist[bin], 1u);
        }
      }
    }
    __syncthreads();
    if (tid < 64) {
      u32 h0 = hist[4 * lane], h1 = hist[4 * lane + 1];
      u32 h2 = hist[4 * lane + 2], h3 = hist[4 * lane + 3];
      u32 L = h0 + h1 + h2 + h3;
      u32 SS = L;                      // inclusive suffix-sum across lanes
#pragma unroll
      for (int off = 1; off < 64; off <<= 1) {
        u32 tv = __shfl_down(SS, off, 64);
        if (lane + off < 64) SS += tv;
      }
      u32 T = SS - L;
      u32 s3 = h3 + T, s2 = h2 + s3, s1 = h1 + s2, s0 = h0 + s1;
      u32 sv[5] = {s0, s1, s2, s3, T};
#pragma unroll
      for (int j = 0; j < 4; ++j) {
        if ((int)sv[j] >= rem && (int)sv[j + 1] < rem) {   // unique crossing bin
          sh_prefix = prefix | ((u32)(4 * lane + j) << shift);
          sh_rem = rem - (int)sv[j + 1];
        }
      }
    }
    __syncthreads();
    prefix = sh_prefix; rem = sh_rem;
  }

  if (tid == 0) sh_cnt = 0;
  __syncthreads();
#pragma unroll
  for (int k = 0; k < 39; ++k) {
    bool live = (k < 38) || (tid < 463);
    u32 v = val[k];
    bool c = live && (v >= prefix);
    u64 mask = __ballot(c);
    if (mask) {
      int leader = __ffsll(mask) - 1;
      int cntw = __popcll(mask);
      int base = 0;
      if (lane == leader) base = atomicAdd(&sh_cnt, cntw);
      base = __shfl(base, leader, 64);
      int p = base + (int)__popcll(mask & ((1ull << lane) - 1ull));
      if (c && p < CAND_CAP)
        key[p] = ((u64)v << 32) | (u32)(~(u32)(tid + k * 1024));
    }
  }
  __syncthreads();
  int cnt = (sh_cnt < CAND_CAP) ? sh_cnt : CAND_CAP;
  for (int t = tid; t < CAND_CAP; t += 1024)
    if (t >= cnt) key[t] = 0ull;
  __syncthreads();

  u32 n = (cnt <= 2048) ? 2048u : (u32)CAND_CAP;
  for (u32 k = 2; k <= n; k <<= 1) {
    for (u32 j = k >> 1; j > 0; j >>= 1) {
      __syncthreads();
      for (u32 t = tid; t < n; t += 1024) {
        u32 ixj = t ^ j;
        if (ixj > t) {
          u64 a = key[t], c = key[ixj];
          bool desc = ((t & k) == 0);
          if (desc ? (a < c) : (a > c)) { key[t] = c; key[ixj] = a; }
        }
      }
    }
  }
  __syncthreads();

  for (int t = tid; t < 2048; t += 1024) {
    unsigned char vf = 0;
    if (t < PRE_NMS) {
      u64 kk = key[t];
      u32 uu = (u32)(kk >> 32);
      float* tb = topbox + ((size_t)b * PRE_NMS + t) * 4;
      if (uu != 0u) {
        u32 idx = ~((u32)kk);
        const float* bp = boxes + ((size_t)b * NANCHORS + idx) * 4;
        tb[0] = bp[0]; tb[1] = bp[1]; tb[2] = bp[2]; tb[3] = bp[3];
        vf = (uu != UNEG) ? 1 : 0;
      } else {
        tb[0] = 0.f; tb[1] = 0.f; tb[2] = 0.f; tb[3] = 0.f;
      }
    }
    validf[t] = vf;
  }
  __syncthreads();
  if (tid < 32) {
    u64 m = 0;
    for (int bit = 0; bit < 64; ++bit) {
      int j = tid * 64 + bit;
      if (j >= PRE_NMS || !validf[j]) m |= (1ull << bit);
    }
    sup0[b * 32 + tid] = m;
  }
}

// ---------------- pairwise IoU suppression bitmask, TRANSPOSED u32 layout ---------------
__global__ __launch_bounds__(256) void iou_kernel(const float* __restrict__ topbox, u32* __restrict__ M32)
{
  int t = blockIdx.x * 256 + threadIdx.x;   // < 64000
  int b = blockIdx.y;
  int w = t / 2000, i = t % 2000;
  const float* tb = topbox + (size_t)b * PRE_NMS * 4;
  const float* bi = tb + (size_t)i * 4;
  float iy1 = bi[0], ix1 = bi[1], iy2 = bi[2], ix2 = bi[3];
  float ai = (iy2 - iy1) * (ix2 - ix1);
  u64 m = 0;
  for (int bit = 0; bit < 64; ++bit) {
    int j = w * 64 + bit;
    if (j < PRE_NMS && j > i) {
      const float* bj = tb + (size_t)j * 4;
      float ty = fmaxf(iy1, bj[0]), tx = fmaxf(ix1, bj[1]);
      float by = fminf(iy2, bj[2]), bx = fminf(ix2, bj[3]);
      float hh = fmaxf(by - ty, 0.f), ww = fmaxf(bx - tx, 0.f);
      float inter = hh * ww;
      float aj = (bj[2] - bj[0]) * (bj[3] - bj[1]);
      float iou = inter / (ai + aj - inter + 1e-12f);
      if (iou > 0.7f) m |= (1ull << bit);
    }
  }
  u32* out = M32 + (size_t)b * MPAD * 64;
  out[(size_t)(2 * w)     * MPAD + i] = (u32)m;
  out[(size_t)(2 * w + 1) * MPAD + i] = (u32)(m >> 32);
}

// ---------------- merged NMS scan (1 wave, distributed regs) + emit top-300 -------------
__global__ __launch_bounds__(320) void final_kernel(
    const u32* __restrict__ M32, const u64* __restrict__ sup0, const float* __restrict__ topbox,
    float* __restrict__ rois, float* __restrict__ roiidx)
{
  int b = blockIdx.x, tid = threadIdx.x;
  __shared__ u32 supl[64];
  __shared__ int ord[POST_NMS];
  __shared__ int cnt_s;

  if (tid < 64) {
    int l = tid;                            // lane l owns u32 word l
    const u32* col = M32 + (size_t)b * MPAD * 64 + (size_t)l * MPAD;
    u32 sup = ((const u32*)sup0)[b * 64 + l];
    uint4 A[16], B[16];
#pragma unroll
    for (int k = 0; k < 16; ++k) A[k] = *(const uint4*)(col + 4 * k);

#define NMS_PROC(buf, cc) do {                                                     \
  _Pragma("unroll")                                                                \
  for (int rr = 0; rr < 64; ++rr) {                                                \
    u32 d = ((rr & 3) == 0) ? buf[rr >> 2].x : ((rr & 3) == 1) ? buf[rr >> 2].y :  \
            ((rr & 3) == 2) ? buf[rr >> 2].z : buf[rr >> 2].w;                     \
    u32 sb = (u32)__builtin_amdgcn_readlane((int)sup, 2 * (cc) + (rr >> 5));       \
    u32 m = ((sb >> (rr & 31)) & 1u) - 1u;                                         \
    sup |= m & d;                                                                  \
  } } while (0)

    for (int c = 0; c < 32; c += 2) {
#pragma unroll
      for (int k = 0; k < 16; ++k) B[k] = *(const uint4*)(col + (c + 1) * 64 + 4 * k);
      NMS_PROC(A, c);
      if (c + 2 < 32) {
#pragma unroll
        for (int k = 0; k < 16; ++k) A[k] = *(const uint4*)(col + (c + 2) * 64 + 4 * k);
      }
      NMS_PROC(B, c + 1);
    }
    supl[l] = sup;
  }
  __syncthreads();
  if (tid == 0) {
    int cnt = 0;
    for (int w = 0; w < 64 && cnt < POST_NMS; ++w) {
      u32 kept = ~supl[w];
      while (kept && cnt < POST_NMS) {
        int bit = __builtin_ctz(kept); kept &= kept - 1;
        ord[cnt++] = w * 32 + bit;
      }
    }
    cnt_s = cnt;
  }
  __syncthreads();
  if (tid < POST_NMS) {
    float v0 = 0.f, v1 = 0.f, v2 = 0.f, v3 = 0.f;
    if (tid < cnt_s) {
      const float* tb = topbox + ((size_t)b * PRE_NMS + ord[tid]) * 4;
      v0 = tb[0]; v1 = tb[1]; v2 = tb[2]; v3 = tb[3];
    }
    float* r = rois + ((size_t)b * POST_NMS + tid) * 4;
    r[0] = v0; r[1] = v1; r[2] = v2; r[3] = v3;
    roiidx[b * POST_NMS + tid] = (float)b;
  }
}

extern "C" void kernel_launch(void* const* d_in, const int* in_sizes, int n_in,
                              void* d_out, int out_size, void* d_ws, size_t ws_size,
                              hipStream_t stream) {
  const float* feat0   = (const float*)d_in[0];
  const float* feat1   = (const float*)d_in[1];
  const float* feat2   = (const float*)d_in[2];
  const float* conv_w  = (const float*)d_in[3];
  const float* conv_b  = (const float*)d_in[4];
  const float* score_w = (const float*)d_in[5];
  const float* score_b = (const float*)d_in[6];
  const float* loc_w   = (const float*)d_in[7];
  const float* loc_b   = (const float*)d_in[8];
  const float* anchors = (const float*)d_in[9];
  const int*   img_h   = (const int*)d_in[10];
  const int*   img_w   = (const int*)d_in[11];

  float* out_f       = (float*)d_out;
  float* out_locs    = out_f;                // 2*39375*4
  float* out_scores  = out_f + 315000;       // 2*39375*2
  float* out_rois    = out_f + 472500;       // 600*4
  float* out_roiidx  = out_f + 474900;       // 600
  float* out_anchors = out_f + 475500;       // 39375*4

  char* p = (char*)d_ws;
  short* xth = (short*)p;     p += (size_t)7084544 * 2;   // padded channels-last fp16 hi
  short* xtl = (short*)p;     p += (size_t)7084544 * 2;   // fp16 lo * 2^11
  short* wsh = (short*)p;     p += (size_t)589824 * 2;    // weights B^T [tap][co][ci] hi
  short* wsl = (short*)p;     p += (size_t)589824 * 2;    // lo * 2^11
  float* proj2 = (float*)p;   p += (size_t)4 * NPIX * 20 * 4;  // head partials [nb*2+wc][P][20]
  float* boxes = (float*)p;   p += (size_t)315000 * 4;    // 2*39375*4
  u32* ukey = (u32*)p;        p += (size_t)78752 * 4;     // 2*39375 (+2 pad: 16B align)
  float* topbox = (float*)p;  p += (size_t)16000 * 4;     // 2*2000*4
  u32* M32 = (u32*)p;         p += (size_t)2 * MPAD * 64 * 4;  // transposed mask
  u64* sup0 = (u64*)p;        p += 64 * 8;
  int* ticket = (int*)p;      p += 256 * 4;               // per-tile decode tickets

  prep_kernel<<<4933, 256, 0, stream>>>(
      feat0, feat1, feat2, conv_w, anchors, xth, xtl, wsh, wsl, out_anchors, ticket);
  gemmconv_kernel<<<416, 256, 0, stream>>>(
      xth, xtl, wsh, wsl, conv_b, loc_w, score_w, loc_b, score_b,
      anchors, img_h, img_w, proj2, ticket,
      out_locs, out_scores, boxes, ukey);
  selectsort_kernel<<<2, 1024, 0, stream>>>(ukey, boxes, topbox, sup0);
  iou_kernel<<<dim3(250, 2), 256, 0, stream>>>(topbox, M32);
  final_kernel<<<2, 320, 0, stream>>>(M32, sup0, topbox, out_rois, out_roiidx);
}

// Round 10
// 348.638 us; speedup vs baseline: 1.1702x; 1.1702x over previous
//
#include <hip/hip_runtime.h>
#include <hip/hip_fp16.h>
#include <cstdint>
#include <cstddef>

typedef unsigned long long u64;
typedef unsigned int u32;
typedef __attribute__((ext_vector_type(8))) _Float16 f16x8;
typedef __attribute__((ext_vector_type(4))) float f32x4;

#define NANCHORS 39375
#define PRE_NMS  2000
#define POST_NMS 300
#define CAND_CAP 4096
#define MPAD 2048          // padded row count of mask matrix
#define UNEG 0x007FFFFFu   // f2u(-inf)
#define NPIX 26250         // 2 batches x 13125 pixels

__device__ __forceinline__ u32 f2u(float f) {
  u32 u = __float_as_uint(f);
  return (u & 0x80000000u) ? ~u : (u | 0x80000000u);
}

// async global->LDS, 16B per lane. LDS dest must be WAVE-UNIFORM base; HW adds lane*16.
#define GLOAD16(gp, lp) __builtin_amdgcn_global_load_lds( \
    (const __attribute__((address_space(1))) u32*)(const void*)(gp), \
    (__attribute__((address_space(3))) u32*)(void*)(lp), 16, 0, 0)

// 16-lane rotate-reduce on the VALU pipe (DPP row_ror) — does NOT touch the LDS pipe.
#define DPP_SUM16(v) do { \
  v += __int_as_float(__builtin_amdgcn_update_dpp(0, __float_as_int(v), 0x128, 0xf, 0xf, true)); \
  v += __int_as_float(__builtin_amdgcn_update_dpp(0, __float_as_int(v), 0x124, 0xf, 0xf, true)); \
  v += __int_as_float(__builtin_amdgcn_update_dpp(0, __float_as_int(v), 0x122, 0xf, 0xf, true)); \
  v += __int_as_float(__builtin_amdgcn_update_dpp(0, __float_as_int(v), 0x121, 0xf, 0xf, true)); \
} while (0)

// ---------------- prep: xsplit | wsplit | ringzero | anchor-copy ------------------------
// All sub-tasks mutually independent; fused into one grid (branch on blockIdx, uniform
// per block so the xsplit barrier is legal). NOTE (R9 journal): do NOT fuse decode into
// gemmconv — the threadfence/ticket + scattered gather degraded the MFMA loop 96->160us.
__global__ __launch_bounds__(256) void prep_kernel(
    const float* __restrict__ f0, const float* __restrict__ f1, const float* __restrict__ f2,
    const float* __restrict__ w, const float* __restrict__ anchors,
    short* __restrict__ xh, short* __restrict__ xl,
    short* __restrict__ wh, short* __restrict__ wl,
    float* __restrict__ out_anchors)
{
  int blk = blockIdx.x;
  int tid = threadIdx.x;
  if (blk < 1656) {
    // ---- xsplit: NCHW f32 -> padded channels-last fp16 hi/lo ----
    __shared__ float tile[64][65];
    int t = blk;
    int HW, W, W2, np; const float* fp; int AB, ABS;
    if (t < 1256)      { HW = 10000; W = 100; W2 = 102; np = 157; fp = f0; AB = 0;       ABS = 2663424; }
    else if (t < 1576) { t -= 1256; HW = 2500; W = 50; W2 = 52; np = 40; fp = f1; AB = 5326848; ABS = 692224; }
    else               { t -= 1576; HW = 625;  W = 25; W2 = 27; np = 10; fp = f2; AB = 6711296; ABS = 186624; }
    int posb = t % np, r = t / np;
    int ci0 = (r & 3) * 64, b = r >> 2;
    int pos0 = posb * 64;
    int lane = tid & 63, wv = tid >> 6;
    int rp = pos0 + lane; if (rp >= HW) rp = HW - 1;
    const float* src = fp + (size_t)(b * 256 + ci0) * HW;
#pragma unroll
    for (int p = 0; p < 16; ++p) {
      int cl = wv * 16 + p;
      tile[cl][lane] = src[(size_t)cl * HW + rp];
    }
    __syncthreads();
    int pix = tid >> 2, cq = tid & 3;
    int pos = pos0 + pix;
    if (pos < HW) {
      int y = pos / W, x = pos - y * W;
      size_t ob = (size_t)AB + (size_t)b * ABS + ((size_t)((y + 1) * W2 + (x + 1))) * 256 + ci0 + cq * 16;
      __align__(16) short hs[16], ls[16];
#pragma unroll
      for (int j = 0; j < 16; ++j) {
        float v = tile[cq * 16 + j][pix];
        __half h = __float2half(v);
        __half l = __float2half((v - __half2float(h)) * 2048.0f);
        hs[j] = __half_as_short(h);
        ls[j] = __half_as_short(l);
      }
      *(int4*)(xh + ob) = ((int4*)hs)[0];
      *(int4*)(xh + ob + 8) = ((int4*)hs)[1];
      *(int4*)(xl + ob) = ((int4*)ls)[0];
      *(int4*)(xl + ob + 8) = ((int4*)ls)[1];
    }
  } else if (blk < 3960) {
    // ---- wsplit: [co][ci][tap] f32 -> B^T [tap][co][ci] fp16 hi/lo ----
    int idx = (blk - 1656) * 256 + tid;        // < 589824 exactly
    int tap = idx >> 16, co = (idx >> 8) & 255, ci = idx & 255;
    float v = w[(size_t)co * 2304 + ci * 9 + tap];
    __half h = __float2half(v);
    __half l = __float2half((v - __half2float(h)) * 2048.0f);
    wh[idx] = __half_as_short(h);
    wl[idx] = __half_as_short(l);
  } else if (blk < 4316) {
    // ---- ringzero: zero the spatial pad ring of xth/xtl ----
    int g = (blk - 3960) * 256 + tid;          // < 91136 = 1424*64 exactly
    int t = g >> 6, ln = g & 63;
    int b = t / 712, i = t % 712;
    int W2, AB, ABS;
    if (i < 404)      { W2 = 102; AB = 0;       ABS = 2663424; }
    else if (i < 608) { i -= 404; W2 = 52; AB = 5326848; ABS = 692224; }
    else              { i -= 608; W2 = 27; AB = 6711296; ABS = 186624; }
    int y, x;
    if (i < W2)          { y = 0;      x = i; }
    else if (i < 2 * W2) { y = W2 - 1; x = i - W2; }
    else { int j = i - 2 * W2; y = 1 + (j >> 1); x = (j & 1) ? (W2 - 1) : 0; }
    size_t base = (size_t)AB + (size_t)b * ABS + ((size_t)(y * W2 + x)) * 256 + ln * 4;
    int2 z = {0, 0};
    *(int2*)(xh + base) = z;
    *(int2*)(xl + base) = z;
  } else {
    // ---- anchor copy ----
    int t = (blk - 4316) * 256 + tid;
    if (t < 157500) out_anchors[t] = anchors[t];
  }
}

// ---------------- conv 3x3 implicit-GEMM on MFMA + fused head projection ---------------
// R8-proven: 256thr/4wave 128x128 tile, A+B LDS-staged, XOR-swizzled (LDS-pipe-bound at
// MfmaUtil ~42-45%; direct-global A regressed to 18% — R5). Epilogue projects 256ch->18
// on VALU (DPP reduce) into proj2[4][NPIX][20]; decode is a SEPARATE kernel (R9's
// in-kernel ticket+fence decode regressed this dispatch 96->160us — do not re-fuse).
__global__ __launch_bounds__(256, 2) void gemmconv_kernel(
    const short* __restrict__ xh, const short* __restrict__ xl,
    const short* __restrict__ wh, const short* __restrict__ wl,
    const float* __restrict__ bias,
    const float* __restrict__ loc_w, const float* __restrict__ score_w,
    float* __restrict__ proj2)
{
  __shared__ __align__(16) short smem[32768];  // Ah[128][64] | Al | Bh[128][64] | Bl

  int lb = (blockIdx.x & 7) * 52 + (blockIdx.x >> 3);
  int HW, W, W2, AB, ABS, lvlbase;
  if (lb < 316)      { HW = 10000; W = 100; W2 = 102; AB = 0;       ABS = 2663424; lvlbase = 0; }
  else if (lb < 396) { lb -= 316; HW = 2500; W = 50; W2 = 52; AB = 5326848; ABS = 692224; lvlbase = 10000; }
  else               { lb -= 396; HW = 625;  W = 25; W2 = 27; AB = 6711296; ABS = 186624; lvlbase = 12500; }
  int mb = lb >> 2, b = (lb >> 1) & 1, nb = lb & 1;
  int pos0 = mb * 128, co0 = nb * 128;

  int tid = threadIdx.x;
  int s = tid & 7, mrow = tid >> 3;
  int aoff[4], boff[4];
#pragma unroll
  for (int i = 0; i < 4; ++i) {
    int m = i * 32 + mrow;
    int pos = pos0 + m; if (pos >= HW) pos = HW - 1;   // tail rows: clamp (store is masked)
    int y = pos / W, x = pos - y * W;
    aoff[i] = AB + b * ABS + (y * W2 + x) * 256 + ((s ^ (m & 7)) << 3);
    boff[i] = ((co0 + m) << 8) + ((s ^ (m & 7)) << 3);
  }
  int wv = tid >> 6, lane = tid & 63;
  int lr = lane & 15, lk = lane >> 4;
  int wr = wv >> 1, wc = wv & 1;
  int rA0 = wr * 64 + lr, rB0 = wc * 64 + lr;
  int cs = (lr & 7) << 4;
  int c0 = ((lk * 16) ^ cs) >> 1;
  int c1 = ((64 + lk * 16) ^ cs) >> 1;

  f32x4 acc1[4][4], acc2[4][4];
  f32x4 zro = {0.f, 0.f, 0.f, 0.f};
#pragma unroll
  for (int i = 0; i < 4; ++i)
#pragma unroll
    for (int j = 0; j < 4; ++j) { acc1[i][j] = zro; acc2[i][j] = zro; }

  for (int cc = 0; cc < 36; ++cc) {
    int tap = cc >> 2, cq = cc & 3;
    int ty = tap / 3, tx = tap - ty * 3;
    int adel = (ty * W2 + tx) * 256 + (cq << 6);
    int bdel = (tap << 16) + (cq << 6);
    if (cc) __syncthreads();
#pragma unroll
    for (int i = 0; i < 4; ++i) {
      int d = i * 2048 + wv * 512;
      GLOAD16(xh + aoff[i] + adel, smem + d);
      GLOAD16(xl + aoff[i] + adel, smem + 8192 + d);
      GLOAD16(wh + boff[i] + bdel, smem + 16384 + d);
      GLOAD16(wl + boff[i] + bdel, smem + 24576 + d);
    }
    __syncthreads();
#pragma unroll
    for (int k2 = 0; k2 < 2; ++k2) {
      int ck = k2 ? c1 : c0;
      f16x8 ah[4], al[4], bh[4], bl[4];
#pragma unroll
      for (int q = 0; q < 4; ++q) {
        int ro = (rA0 + q * 16) * 64 + ck;
        ah[q] = *(const f16x8*)(smem + ro);
        al[q] = *(const f16x8*)(smem + 8192 + ro);
        int rb = (rB0 + q * 16) * 64 + ck;
        bh[q] = *(const f16x8*)(smem + 16384 + rb);
        bl[q] = *(const f16x8*)(smem + 24576 + rb);
      }
#pragma unroll
      for (int m4 = 0; m4 < 4; ++m4)
#pragma unroll
        for (int n4 = 0; n4 < 4; ++n4) {
          acc1[m4][n4] = __builtin_amdgcn_mfma_f32_16x16x32_f16(ah[m4], bh[n4], acc1[m4][n4], 0, 0, 0);
          acc2[m4][n4] = __builtin_amdgcn_mfma_f32_16x16x32_f16(ah[m4], bl[n4], acc2[m4][n4], 0, 0, 0);
          acc2[m4][n4] = __builtin_amdgcn_mfma_f32_16x16x32_f16(al[m4], bh[n4], acc2[m4][n4], 0, 0, 0);
        }
    }
  }

  // ---- fused head projection epilogue (no h store) ----
  float br[4];
#pragma unroll
  for (int n4 = 0; n4 < 4; ++n4) br[n4] = bias[co0 + wc * 64 + n4 * 16 + lr];
  float* pslot = proj2 + (size_t)(nb * 2 + wc) * NPIX * 20;
  int Pbase = b * 13125 + lvlbase;

#pragma unroll 1
  for (int half = 0; half < 2; ++half) {
    float wpr[4][9];
#pragma unroll
    for (int n4 = 0; n4 < 4; ++n4) {
      int c = co0 + wc * 64 + n4 * 16 + lr;
#pragma unroll
      for (int oo = 0; oo < 9; ++oo) {
        int o = half * 9 + oo;
        wpr[n4][oo] = (o < 12) ? loc_w[o * 256 + c] : score_w[(o - 12) * 256 + c];
      }
    }
#pragma unroll
    for (int m4 = 0; m4 < 4; ++m4) {
#pragma unroll
      for (int j = 0; j < 4; ++j) {
        int pos = pos0 + wr * 64 + m4 * 16 + lk * 4 + j;   // C: row=(lane>>4)*4+reg
        bool ok = pos < HW;
        float po[9];
#pragma unroll
        for (int oo = 0; oo < 9; ++oo) po[oo] = 0.f;
#pragma unroll
        for (int n4 = 0; n4 < 4; ++n4) {
          float h = acc1[m4][n4][j] + acc2[m4][n4][j] * 4.8828125e-4f + br[n4];
          h = ok ? fmaxf(h, 0.f) : 0.f;
#pragma unroll
          for (int oo = 0; oo < 9; ++oo) po[oo] = fmaf(h, wpr[n4][oo], po[oo]);
        }
#pragma unroll
        for (int oo = 0; oo < 9; ++oo) DPP_SUM16(po[oo]);
        if (ok && lr < 9) {
          float out = po[0];                   // static-index select (rule #20)
#pragma unroll
          for (int oo = 1; oo < 9; ++oo) if (lr == oo) out = po[oo];
          pslot[(size_t)(Pbase + pos) * 20 + half * 9 + lr] = out;
        }
      }
    }
  }
}

// ---------------- decode: sum 4 projection partials, bias, softmax, box decode, key ----
__global__ __launch_bounds__(256) void decode_kernel(
    const float* __restrict__ proj2, const float* __restrict__ loc_b, const float* __restrict__ score_b,
    const float* __restrict__ anchors, const int* __restrict__ imgh, const int* __restrict__ imgw,
    float* __restrict__ out_locs, float* __restrict__ out_scores,
    float* __restrict__ boxes, u32* __restrict__ ukey)
{
  int P = blockIdx.x * 256 + threadIdx.x;
  if (P >= NPIX) return;
  int b = P / 13125, r = P % 13125;
  int pos, base_row;
  if (r < 10000)      { pos = r;         base_row = 0; }
  else if (r < 12500) { pos = r - 10000; base_row = 30000; }
  else                { pos = r - 12500; base_row = 37500; }

  float sarr[18];
#pragma unroll
  for (int o = 0; o < 18; ++o)
    sarr[o] = proj2[(size_t)P * 20 + o] + proj2[(size_t)NPIX * 20 + (size_t)P * 20 + o]
            + proj2[(size_t)2 * NPIX * 20 + (size_t)P * 20 + o]
            + proj2[(size_t)3 * NPIX * 20 + (size_t)P * 20 + o];

  float IH = (float)(*imgh), IW = (float)(*imgw);
#pragma unroll
  for (int a = 0; a < 3; ++a) {
    float l0 = sarr[4 * a + 0] + loc_b[4 * a + 0];
    float l1 = sarr[4 * a + 1] + loc_b[4 * a + 1];
    float l2 = sarr[4 * a + 2] + loc_b[4 * a + 2];
    float l3 = sarr[4 * a + 3] + loc_b[4 * a + 3];
    float sc0 = sarr[12 + 2 * a + 0] + score_b[2 * a + 0];
    float sc1 = sarr[12 + 2 * a + 1] + score_b[2 * a + 1];

    int row = base_row + pos * 3 + a;
    size_t g = (size_t)b * NANCHORS + row;
    *(float4*)(out_locs + g * 4) = make_float4(l0, l1, l2, l3);
    out_scores[g * 2 + 0] = sc0; out_scores[g * 2 + 1] = sc1;

    float mx = fmaxf(sc0, sc1);
    float e0 = expf(sc0 - mx), e1 = expf(sc1 - mx);
    float fg = e1 / (e0 + e1);

    const float* an = anchors + (size_t)row * 4;
    float a0 = an[0], a1 = an[1], a2 = an[2], a3 = an[3];
    float sh = a2 - a0, sw = a3 - a1;
    float cy = a0 + 0.5f * sh, cx = a1 + 0.5f * sw;
    float ncy = l0 * sh + cy, ncx = l1 * sw + cx;
    float nh = expf(l2) * sh, nw = expf(l3) * sw;
    float y1 = fminf(fmaxf(ncy - 0.5f * nh, 0.f), IH);
    float x1 = fminf(fmaxf(ncx - 0.5f * nw, 0.f), IW);
    float y2 = fminf(fmaxf(ncy + 0.5f * nh, 0.f), IH);
    float x2 = fminf(fmaxf(ncx + 0.5f * nw, 0.f), IW);
    bool valid = ((y2 - y1) >= 16.0f) && ((x2 - x1) >= 16.0f);
    float scm = valid ? fg : -__builtin_inff();

    *(float4*)(boxes + g * 4) = make_float4(y1, x1, y2, x2);
    ukey[g] = f2u(scm);
  }
}

// ---------------- merged radix-select + bitonic sort, v2 --------------------------------
__global__ __launch_bounds__(1024) void selectsort_kernel(
    const u32* __restrict__ ukey, const float* __restrict__ boxes,
    float* __restrict__ topbox, u64* __restrict__ sup0)
{
  int b = blockIdx.x, tid = threadIdx.x;
  int lane = tid & 63;
  const u32* u = ukey + (size_t)b * NANCHORS;
  __shared__ u32 hist[256];
  __shared__ u32 sh_prefix;
  __shared__ int sh_rem;
  __shared__ int sh_cnt;
  __shared__ u64 key[CAND_CAP];
  __shared__ unsigned char validf[2048];

  u32 val[39];                         // 39375 = 38*1024 + 463
#pragma unroll
  for (int k = 0; k < 38; ++k) val[k] = u[tid + k * 1024];
  val[38] = (tid < 463) ? u[tid + 38912] : 0u;

  u32 prefix = 0; int rem = PRE_NMS;
#pragma unroll 1
  for (int pass = 0; pass < 4; ++pass) {
    int shift = 24 - 8 * pass;
    if (tid < 256) hist[tid] = 0;
    __syncthreads();
    u32 himask = (pass == 0) ? 0u : (0xFFFFFFFFu << (shift + 8));
    u32 pmask = prefix & himask;
#pragma unroll
    for (int k = 0; k < 39; ++k) {
      bool live = (k < 38) || (tid < 463);
      u32 v = val[k];
      bool m = live && ((v & himask) == pmask);
      u32 bin = (v >> shift) & 255u;
      u64 actm = __ballot(m);
      if (actm) {
        int src = __ffsll(actm) - 1;
        u32 binf = __shfl(bin, src, 64);
        bool same = m && (bin == binf);
        u64 sm = __ballot(same);
        if (same) {
          if (lane == __ffsll(sm) - 1)
            atomicAdd(&hist[binf], (u32)__popcll(sm));
        } else if (m) {
          atomicAdd(&hist[bin], 1u);
        }
      }
    }
    __syncthreads();
    if (tid < 64) {
      u32 h0 = hist[4 * lane], h1 = hist[4 * lane + 1];
      u32 h2 = hist[4 * lane + 2], h3 = hist[4 * lane + 3];
      u32 L = h0 + h1 + h2 + h3;
      u32 SS = L;                      // inclusive suffix-sum across lanes
#pragma unroll
      for (int off = 1; off < 64; off <<= 1) {
        u32 tv = __shfl_down(SS, off, 64);
        if (lane + off < 64) SS += tv;
      }
      u32 T = SS - L;
      u32 s3 = h3 + T, s2 = h2 + s3, s1 = h1 + s2, s0 = h0 + s1;
      u32 sv[5] = {s0, s1, s2, s3, T};
#pragma unroll
      for (int j = 0; j < 4; ++j) {
        if ((int)sv[j] >= rem && (int)sv[j + 1] < rem) {   // unique crossing bin
          sh_prefix = prefix | ((u32)(4 * lane + j) << shift);
          sh_rem = rem - (int)sv[j + 1];
        }
      }
    }
    __syncthreads();
    prefix = sh_prefix; rem = sh_rem;
  }

  if (tid == 0) sh_cnt = 0;
  __syncthreads();
#pragma unroll
  for (int k = 0; k < 39; ++k) {
    bool live = (k < 38) || (tid < 463);
    u32 v = val[k];
    bool c = live && (v >= prefix);
    u64 mask = __ballot(c);
    if (mask) {
      int leader = __ffsll(mask) - 1;
      int cntw = __popcll(mask);
      int base = 0;
      if (lane == leader) base = atomicAdd(&sh_cnt, cntw);
      base = __shfl(base, leader, 64);
      int p = base + (int)__popcll(mask & ((1ull << lane) - 1ull));
      if (c && p < CAND_CAP)
        key[p] = ((u64)v << 32) | (u32)(~(u32)(tid + k * 1024));
    }
  }
  __syncthreads();
  int cnt = (sh_cnt < CAND_CAP) ? sh_cnt : CAND_CAP;
  for (int t = tid; t < CAND_CAP; t += 1024)
    if (t >= cnt) key[t] = 0ull;
  __syncthreads();

  u32 n = (cnt <= 2048) ? 2048u : (u32)CAND_CAP;
  for (u32 k = 2; k <= n; k <<= 1) {
    for (u32 j = k >> 1; j > 0; j >>= 1) {
      __syncthreads();
      for (u32 t = tid; t < n; t += 1024) {
        u32 ixj = t ^ j;
        if (ixj > t) {
          u64 a = key[t], c = key[ixj];
          bool desc = ((t & k) == 0);
          if (desc ? (a < c) : (a > c)) { key[t] = c; key[ixj] = a; }
        }
      }
    }
  }
  __syncthreads();

  for (int t = tid; t < 2048; t += 1024) {
    unsigned char vf = 0;
    if (t < PRE_NMS) {
      u64 kk = key[t];
      u32 uu = (u32)(kk >> 32);
      float* tb = topbox + ((size_t)b * PRE_NMS + t) * 4;
      if (uu != 0u) {
        u32 idx = ~((u32)kk);
        const float* bp = boxes + ((size_t)b * NANCHORS + idx) * 4;
        tb[0] = bp[0]; tb[1] = bp[1]; tb[2] = bp[2]; tb[3] = bp[3];
        vf = (uu != UNEG) ? 1 : 0;
      } else {
        tb[0] = 0.f; tb[1] = 0.f; tb[2] = 0.f; tb[3] = 0.f;
      }
    }
    validf[t] = vf;
  }
  __syncthreads();
  if (tid < 32) {
    u64 m = 0;
    for (int bit = 0; bit < 64; ++bit) {
      int j = tid * 64 + bit;
      if (j >= PRE_NMS || !validf[j]) m |= (1ull << bit);
    }
    sup0[b * 32 + tid] = m;
  }
}

// ---------------- pairwise IoU bitmask v3: block-per-wordcol, LDS-staged j-boxes --------
// grid (256,2): blockIdx.x>>3 = word column w (0..31); (blockIdx.x&7)*256+tid = row i.
// The 64 j-boxes of column w are shared by the whole block -> staged once in LDS
// (broadcast reads, conflict-free) instead of 256x redundant global re-reads.
__global__ __launch_bounds__(256) void iou_kernel(const float* __restrict__ topbox, u32* __restrict__ M32)
{
  __shared__ float4 bx[64];
  int b = blockIdx.y;
  int w = blockIdx.x >> 3;
  int i = (blockIdx.x & 7) * 256 + threadIdx.x;   // 0..2047
  const float4* tb = (const float4*)(topbox + (size_t)b * PRE_NMS * 4);
  if (threadIdx.x < 64) {
    int j = w * 64 + threadIdx.x;
    bx[threadIdx.x] = (j < PRE_NMS) ? tb[j] : make_float4(0.f, 0.f, 0.f, 0.f);
  }
  __syncthreads();
  if (i >= PRE_NMS) return;
  float4 bi = tb[i];
  float iy1 = bi.x, ix1 = bi.y, iy2 = bi.z, ix2 = bi.w;
  float ai = (iy2 - iy1) * (ix2 - ix1);
  u64 m = 0;
#pragma unroll 8
  for (int bit = 0; bit < 64; ++bit) {
    int j = w * 64 + bit;
    if (j < PRE_NMS && j > i) {
      float4 bj = bx[bit];
      float ty = fmaxf(iy1, bj.x), tx = fmaxf(ix1, bj.y);
      float by = fminf(iy2, bj.z), bxx = fminf(ix2, bj.w);
      float hh = fmaxf(by - ty, 0.f), ww = fmaxf(bxx - tx, 0.f);
      float inter = hh * ww;
      float aj = (bj.z - bj.x) * (bj.w - bj.y);
      float iou = inter / (ai + aj - inter + 1e-12f);
      if (iou > 0.7f) m |= (1ull << bit);
    }
  }
  u32* out = M32 + (size_t)b * MPAD * 64;
  out[(size_t)(2 * w)     * MPAD + i] = (u32)m;
  out[(size_t)(2 * w + 1) * MPAD + i] = (u32)(m >> 32);
}

// ---------------- merged NMS scan (1 wave, distributed regs) + emit top-300 -------------
__global__ __launch_bounds__(320) void final_kernel(
    const u32* __restrict__ M32, const u64* __restrict__ sup0, const float* __restrict__ topbox,
    float* __restrict__ rois, float* __restrict__ roiidx)
{
  int b = blockIdx.x, tid = threadIdx.x;
  __shared__ u32 supl[64];
  __shared__ int ord[POST_NMS];
  __shared__ int cnt_s;

  if (tid < 64) {
    int l = tid;                            // lane l owns u32 word l
    const u32* col = M32 + (size_t)b * MPAD * 64 + (size_t)l * MPAD;
    u32 sup = ((const u32*)sup0)[b * 64 + l];
    uint4 A[16], B[16];
#pragma unroll
    for (int k = 0; k < 16; ++k) A[k] = *(const uint4*)(col + 4 * k);

#define NMS_PROC(buf, cc) do {                                                     \
  _Pragma("unroll")                                                                \
  for (int rr = 0; rr < 64; ++rr) {                                                \
    u32 d = ((rr & 3) == 0) ? buf[rr >> 2].x : ((rr & 3) == 1) ? buf[rr >> 2].y :  \
            ((rr & 3) == 2) ? buf[rr >> 2].z : buf[rr >> 2].w;                     \
    u32 sb = (u32)__builtin_amdgcn_readlane((int)sup, 2 * (cc) + (rr >> 5));       \
    u32 m = ((sb >> (rr & 31)) & 1u) - 1u;                                         \
    sup |= m & d;                                                                  \
  } } while (0)

    for (int c = 0; c < 32; c += 2) {
#pragma unroll
      for (int k = 0; k < 16; ++k) B[k] = *(const uint4*)(col + (c + 1) * 64 + 4 * k);
      NMS_PROC(A, c);
      if (c + 2 < 32) {
#pragma unroll
        for (int k = 0; k < 16; ++k) A[k] = *(const uint4*)(col + (c + 2) * 64 + 4 * k);
      }
      NMS_PROC(B, c + 1);
    }
    supl[l] = sup;
  }
  __syncthreads();
  if (tid == 0) {
    int cnt = 0;
    for (int w = 0; w < 64 && cnt < POST_NMS; ++w) {
      u32 kept = ~supl[w];
      while (kept && cnt < POST_NMS) {
        int bit = __builtin_ctz(kept); kept &= kept - 1;
        ord[cnt++] = w * 32 + bit;
      }
    }
    cnt_s = cnt;
  }
  __syncthreads();
  if (tid < POST_NMS) {
    float v0 = 0.f, v1 = 0.f, v2 = 0.f, v3 = 0.f;
    if (tid < cnt_s) {
      const float* tb = topbox + ((size_t)b * PRE_NMS + ord[tid]) * 4;
      v0 = tb[0]; v1 = tb[1]; v2 = tb[2]; v3 = tb[3];
    }
    float* r = rois + ((size_t)b * POST_NMS + tid) * 4;
    r[0] = v0; r[1] = v1; r[2] = v2; r[3] = v3;
    roiidx[b * POST_NMS + tid] = (float)b;
  }
}

extern "C" void kernel_launch(void* const* d_in, const int* in_sizes, int n_in,
                              void* d_out, int out_size, void* d_ws, size_t ws_size,
                              hipStream_t stream) {
  const float* feat0   = (const float*)d_in[0];
  const float* feat1   = (const float*)d_in[1];
  const float* feat2   = (const float*)d_in[2];
  const float* conv_w  = (const float*)d_in[3];
  const float* conv_b  = (const float*)d_in[4];
  const float* score_w = (const float*)d_in[5];
  const float* score_b = (const float*)d_in[6];
  const float* loc_w   = (const float*)d_in[7];
  const float* loc_b   = (const float*)d_in[8];
  const float* anchors = (const float*)d_in[9];
  const int*   img_h   = (const int*)d_in[10];
  const int*   img_w   = (const int*)d_in[11];

  float* out_f       = (float*)d_out;
  float* out_locs    = out_f;                // 2*39375*4
  float* out_scores  = out_f + 315000;       // 2*39375*2
  float* out_rois    = out_f + 472500;       // 600*4
  float* out_roiidx  = out_f + 474900;       // 600
  float* out_anchors = out_f + 475500;       // 39375*4

  char* p = (char*)d_ws;
  short* xth = (short*)p;     p += (size_t)7084544 * 2;   // padded channels-last fp16 hi
  short* xtl = (short*)p;     p += (size_t)7084544 * 2;   // fp16 lo * 2^11
  short* wsh = (short*)p;     p += (size_t)589824 * 2;    // weights B^T [tap][co][ci] hi
  short* wsl = (short*)p;     p += (size_t)589824 * 2;    // lo * 2^11
  float* proj2 = (float*)p;   p += (size_t)4 * NPIX * 20 * 4;  // head partials [nb*2+wc][P][20]
  float* boxes = (float*)p;   p += (size_t)315000 * 4;    // 2*39375*4
  u32* ukey = (u32*)p;        p += (size_t)78752 * 4;     // 2*39375 (+2 pad: 16B align)
  float* topbox = (float*)p;  p += (size_t)16000 * 4;     // 2*2000*4
  u32* M32 = (u32*)p;         p += (size_t)2 * MPAD * 64 * 4;  // transposed mask
  u64* sup0 = (u64*)p;        p += 64 * 8;

  prep_kernel<<<4932, 256, 0, stream>>>(
      feat0, feat1, feat2, conv_w, anchors, xth, xtl, wsh, wsl, out_anchors);
  gemmconv_kernel<<<416, 256, 0, stream>>>(xth, xtl, wsh, wsl, conv_b, loc_w, score_w, proj2);
  decode_kernel<<<(NPIX + 255) / 256, 256, 0, stream>>>(
      proj2, loc_b, score_b, anchors, img_h, img_w,
      out_locs, out_scores, boxes, ukey);
  selectsort_kernel<<<2, 1024, 0, stream>>>(ukey, boxes, topbox, sup0);
  iou_kernel<<<dim3(256, 2), 256, 0, stream>>>(topbox, M32);
  final_kernel<<<2, 320, 0, stream>>>(M32, sup0, topbox, out_rois, out_roiidx);
}